// Round 1
// baseline (17609.564 us; speedup 1.0000x reference)
//
#include <hip/hip_runtime.h>
#include <cmath>

typedef unsigned short u16;
typedef __attribute__((ext_vector_type(4))) float f32x4;
typedef __attribute__((ext_vector_type(8))) __bf16 bf16x8;
typedef unsigned short u16x4 __attribute__((ext_vector_type(4)));
typedef unsigned short u16x8 __attribute__((ext_vector_type(8)));

#define T_STEPS 512
#define NBLK 64          // blocks in persistent recurrent kernel
#define FINAL_OFF 33554432u  // 512*64*1024

// ---------------- workspace layout (bytes) ----------------
#define OFF_XR   0ull
#define OFF_XZ   (OFF_XR + 67108864ull)     // 512*64*1024 * 2B each
#define OFF_XH   (OFF_XZ + 67108864ull)
#define OFF_WXRT (OFF_XH + 67108864ull)     // 1024*1024*2B each
#define OFF_WXZT (OFF_WXRT + 2097152ull)
#define OFF_WXHT (OFF_WXZT + 2097152ull)
#define OFF_WHRT (OFF_WXHT + 2097152ull)
#define OFF_WHZT (OFF_WHRT + 2097152ull)
#define OFF_WHHT (OFF_WHZT + 2097152ull)
#define OFF_HBF  (OFF_WHHT + 2097152ull)    // 64*1024 bf16
#define OFF_RHBF (OFF_HBF + 131072ull)      // 64*1024 bf16
#define OFF_HF32 (OFF_RHBF + 131072ull)     // 64*1024 f32
#define OFF_ZBUF (OFF_HF32 + 262144ull)     // 64*1024 f32
#define OFF_BAR  (OFF_ZBUF + 262144ull)     // barrier words

// ---------------- helpers ----------------
__device__ __forceinline__ u16 f2bf(float f) {
    unsigned u = __builtin_bit_cast(unsigned, f);
    unsigned r = (u + 0x7FFFu + ((u >> 16) & 1u)) >> 16;
    return (u16)r;
}
__device__ __forceinline__ float bf2f(u16 h) {
    unsigned u = ((unsigned)h) << 16;
    return __builtin_bit_cast(float, u);
}
__device__ __forceinline__ bf16x8 ldb(const u16* p) {
    return *(const bf16x8*)p;
}

// sense-reversal grid barrier; bar[0]=count, bar[1]=generation
__device__ __forceinline__ void gridbar(unsigned* bar) {
    __syncthreads();
    if (threadIdx.x == 0) {
        __threadfence();  // release: flush this XCD's L2 so other XCDs see our stores
        unsigned old = __hip_atomic_load(&bar[1], __ATOMIC_RELAXED, __HIP_MEMORY_SCOPE_AGENT);
        unsigned prev = __hip_atomic_fetch_add(&bar[0], 1u, __ATOMIC_ACQ_REL, __HIP_MEMORY_SCOPE_AGENT);
        if (prev == NBLK - 1) {
            __hip_atomic_store(&bar[0], 0u, __ATOMIC_RELAXED, __HIP_MEMORY_SCOPE_AGENT);
            __hip_atomic_fetch_add(&bar[1], 1u, __ATOMIC_RELEASE, __HIP_MEMORY_SCOPE_AGENT);
        } else {
            while (__hip_atomic_load(&bar[1], __ATOMIC_RELAXED, __HIP_MEMORY_SCOPE_AGENT) == old) {
                __builtin_amdgcn_s_sleep(1);
            }
        }
        __threadfence();  // acquire: invalidate stale L1/L2 before reading others' data
    }
    __syncthreads();
}

// ---------------- phase 0: transpose + fp32->bf16 convert, [K][N] -> [N][K] ----------------
__global__ __launch_bounds__(256) void transpose_cvt(
    const float* __restrict__ W0, const float* __restrict__ W1, const float* __restrict__ W2,
    const float* __restrict__ W3, const float* __restrict__ W4, const float* __restrict__ W5,
    u16* __restrict__ D0, u16* __restrict__ D1, u16* __restrict__ D2,
    u16* __restrict__ D3, u16* __restrict__ D4, u16* __restrict__ D5,
    unsigned* __restrict__ bar)
{
    const float* S[6] = {W0, W1, W2, W3, W4, W5};
    u16* D[6] = {D0, D1, D2, D3, D4, D5};
    int z = blockIdx.z;
    const float* W = S[z];
    u16* Dt = D[z];
    __shared__ float tile[32][33];
    int bx = blockIdx.x * 32, by = blockIdx.y * 32;  // bx: n-base, by: k-base
    int tx = threadIdx.x & 31, ty = threadIdx.x >> 5;
    for (int i = ty; i < 32; i += 8)
        tile[i][tx] = W[(size_t)(by + i) * 1024 + bx + tx];
    __syncthreads();
    for (int i = ty; i < 32; i += 8)
        Dt[(size_t)(bx + i) * 1024 + by + tx] = f2bf(tile[tx][i]);
    if (blockIdx.x == 0 && blockIdx.y == 0 && z == 0 && threadIdx.x < 2)
        bar[threadIdx.x] = 0u;
}

// ---------------- phase 1: X @ Wx* + b -> bf16 projections ----------------
// grid: (8 n-blocks, 256 m-blocks, 3 mats); block 256 thr = 4 waves; tile 128x128, BK=64
__global__ __launch_bounds__(256, 2) void proj_gemm(
    const float* __restrict__ X,
    const u16* __restrict__ Wt0, const u16* __restrict__ Wt1, const u16* __restrict__ Wt2,
    const float* __restrict__ b0, const float* __restrict__ b1, const float* __restrict__ b2,
    u16* __restrict__ P0, u16* __restrict__ P1, u16* __restrict__ P2)
{
    int z = blockIdx.z;
    const u16* Wt = (z == 0) ? Wt0 : (z == 1) ? Wt1 : Wt2;
    const float* bias = (z == 0) ? b0 : (z == 1) ? b1 : b2;
    u16* P = (z == 0) ? P0 : (z == 1) ? P1 : P2;

    __shared__ u16 Asm[128][72];  // 64 + 16B pad -> 2-way bank aliasing (free)
    __shared__ u16 Bsm[128][72];

    int tid = threadIdx.x, lane = tid & 63, w = tid >> 6;
    int m0 = blockIdx.y * 128, n0 = blockIdx.x * 128;
    int mw = (w >> 1) * 64, nw = (w & 1) * 64;
    int l15 = lane & 15, lq = lane >> 4;

    f32x4 zero = {0.f, 0.f, 0.f, 0.f};
    f32x4 acc[4][4];
    #pragma unroll
    for (int mi = 0; mi < 4; ++mi)
        #pragma unroll
        for (int nj = 0; nj < 4; ++nj) acc[mi][nj] = zero;

    for (int k0 = 0; k0 < 1024; k0 += 64) {
        // stage A tile (fp32 -> bf16)
        #pragma unroll
        for (int i = 0; i < 8; ++i) {
            int flat = i * 256 + tid;
            int r = flat >> 4, c4 = flat & 15;
            float4 v = *(const float4*)(X + (size_t)(m0 + r) * 1024 + k0 + c4 * 4);
            u16x4 pk = {f2bf(v.x), f2bf(v.y), f2bf(v.z), f2bf(v.w)};
            *(u16x4*)&Asm[r][c4 * 4] = pk;
        }
        // stage B tile (already bf16, [n][k])
        #pragma unroll
        for (int i = 0; i < 4; ++i) {
            int flat = i * 256 + tid;
            int n = flat >> 3, seg = flat & 7;
            *(u16x8*)&Bsm[n][seg * 8] = *(const u16x8*)(Wt + (size_t)(n0 + n) * 1024 + k0 + seg * 8);
        }
        __syncthreads();
        #pragma unroll
        for (int kk = 0; kk < 2; ++kk) {
            bf16x8 af[4], bg[4];
            #pragma unroll
            for (int mi = 0; mi < 4; ++mi)
                af[mi] = ldb(&Asm[mw + mi * 16 + l15][kk * 32 + lq * 8]);
            #pragma unroll
            for (int nj = 0; nj < 4; ++nj)
                bg[nj] = ldb(&Bsm[nw + nj * 16 + l15][kk * 32 + lq * 8]);
            #pragma unroll
            for (int mi = 0; mi < 4; ++mi)
                #pragma unroll
                for (int nj = 0; nj < 4; ++nj)
                    acc[mi][nj] = __builtin_amdgcn_mfma_f32_16x16x32_bf16(af[mi], bg[nj], acc[mi][nj], 0, 0, 0);
        }
        __syncthreads();
    }
    // epilogue: + bias, -> bf16
    #pragma unroll
    for (int mi = 0; mi < 4; ++mi)
        #pragma unroll
        for (int nj = 0; nj < 4; ++nj)
            #pragma unroll
            for (int r = 0; r < 4; ++r) {
                int m = m0 + mw + mi * 16 + lq * 4 + r;
                int n = n0 + nw + nj * 16 + l15;
                float v = acc[mi][nj][r] + bias[n];
                P[(size_t)m * 1024 + n] = f2bf(v);
            }
}

// ---------------- phase 2: persistent recurrent kernel ----------------
// 64 blocks x 256 thr. Stage1: block b covers 32 cols of [R|Z] (b<32 -> R, else Z),
// W slice persistent in LDS (XOR-swizzled 16B chunks, 64KiB). Stage2: block b covers
// 16 cols of H, W_hh read from global (L2-resident slice).
__global__ __launch_bounds__(256, 1) void gru_rec(
    const u16* __restrict__ XR, const u16* __restrict__ XZ, const u16* __restrict__ XH,
    const u16* __restrict__ Whrt, const u16* __restrict__ Whzt, const u16* __restrict__ Whht,
    const float* __restrict__ state,
    u16* __restrict__ hbf, u16* __restrict__ rhbf,
    float* __restrict__ hf32, float* __restrict__ Zbuf,
    unsigned* __restrict__ bar, float* __restrict__ out)
{
    __shared__ u16 Wrz[32 * 1024];  // 64 KiB, rows = 32 gate-cols, swizzled 16B chunks

    int b = blockIdx.x, tid = threadIdx.x;
    int lane = tid & 63, mi = tid >> 6;
    int n15 = lane & 15, q = lane >> 4;
    int key = n15 & 7;

    // load persistent stage-1 weight slice into LDS (swizzled)
    {
        int row = tid >> 3, seg = tid & 7;
        const u16* wsrc = (b < 32) ? (Whrt + (size_t)(32 * b + row) * 1024)
                                   : (Whzt + (size_t)(32 * (b - 32) + row) * 1024);
        #pragma unroll
        for (int v = 0; v < 16; ++v) {
            int chunk = seg * 16 + v;           // 16B chunk index within row (128 chunks)
            int phys = chunk ^ (row & 7);
            *(u16x8*)&Wrz[row * 1024 + phys * 8] = *(const u16x8*)(wsrc + chunk * 8);
        }
    }
    // init h from input state
    for (int i = b * 256 + tid; i < 65536; i += NBLK * 256) {
        float v = state[i];
        hf32[i] = v;
        hbf[i] = f2bf(v);
    }
    __syncthreads();
    gridbar(bar);

    int nb1 = 32 * (b & 31);          // stage1 col base within its gate
    const u16* Xg = (b < 32) ? XR : XZ;
    int nb2 = 16 * b;                 // stage2 col base
    int rowA = mi * 16 + n15;         // A-fragment row (batch index) for this lane

    for (int t = 0; t < T_STEPS; ++t) {
        // ---------- stage 1: R,Z = sigmoid(Xg[t] + h @ W) ----------
        {
            const u16* ap = hbf + rowA * 1024 + q * 8;
            const u16* base0 = Wrz + (size_t)n15 * 1024;
            const u16* base1 = Wrz + (size_t)(16 + n15) * 1024;
            f32x4 a0a = {0.f,0.f,0.f,0.f}, a0b = {0.f,0.f,0.f,0.f};
            f32x4 a1a = {0.f,0.f,0.f,0.f}, a1b = {0.f,0.f,0.f,0.f};
            bf16x8 Ab[2][8], B0b[2][8], B1b[2][8];
            #pragma unroll
            for (int j = 0; j < 8; ++j) {
                Ab[0][j] = ldb(ap + j * 32);
                B0b[0][j] = ldb(base0 + (((j * 4 + q) ^ key) << 3));
                B1b[0][j] = ldb(base1 + (((j * 4 + q) ^ key) << 3));
            }
            #pragma unroll
            for (int g = 0; g < 4; ++g) {
                int cur = g & 1, nxt = cur ^ 1;
                if (g < 3) {
                    #pragma unroll
                    for (int j = 0; j < 8; ++j) {
                        int s = (g + 1) * 8 + j;
                        Ab[nxt][j] = ldb(ap + s * 32);
                        B0b[nxt][j] = ldb(base0 + (((s * 4 + q) ^ key) << 3));
                        B1b[nxt][j] = ldb(base1 + (((s * 4 + q) ^ key) << 3));
                    }
                }
                #pragma unroll
                for (int j = 0; j < 8; ++j) {
                    if (j & 1) {
                        a0b = __builtin_amdgcn_mfma_f32_16x16x32_bf16(Ab[cur][j], B0b[cur][j], a0b, 0, 0, 0);
                        a1b = __builtin_amdgcn_mfma_f32_16x16x32_bf16(Ab[cur][j], B1b[cur][j], a1b, 0, 0, 0);
                    } else {
                        a0a = __builtin_amdgcn_mfma_f32_16x16x32_bf16(Ab[cur][j], B0b[cur][j], a0a, 0, 0, 0);
                        a1a = __builtin_amdgcn_mfma_f32_16x16x32_bf16(Ab[cur][j], B1b[cur][j], a1a, 0, 0, 0);
                    }
                }
            }
            f32x4 r0 = a0a + a0b, r1 = a1a + a1b;
            #pragma unroll
            for (int j = 0; j < 2; ++j) {
                f32x4 rr = j ? r1 : r0;
                int n = nb1 + j * 16 + n15;
                #pragma unroll
                for (int r = 0; r < 4; ++r) {
                    int row = mi * 16 + q * 4 + r;
                    int idx = row * 1024 + n;
                    float pre = rr[r] + bf2f(Xg[(size_t)t * 65536 + idx]);
                    float gate = 1.f / (1.f + expf(-pre));
                    if (b < 32) rhbf[idx] = f2bf(gate * hf32[idx]);
                    else        Zbuf[idx] = gate;
                }
            }
        }
        gridbar(bar);
        // ---------- stage 2: Hhat = tanh(Xh[t] + (R*h) @ Whh); blend ----------
        {
            const u16* ap = rhbf + rowA * 1024 + q * 8;
            const u16* bp = Whht + (size_t)(nb2 + n15) * 1024 + q * 8;
            f32x4 c0 = {0.f,0.f,0.f,0.f}, c1 = {0.f,0.f,0.f,0.f};
            bf16x8 Ab[2][8], Bb[2][8];
            #pragma unroll
            for (int j = 0; j < 8; ++j) {
                Ab[0][j] = ldb(ap + j * 32);
                Bb[0][j] = ldb(bp + j * 32);
            }
            #pragma unroll
            for (int g = 0; g < 4; ++g) {
                int cur = g & 1, nxt = cur ^ 1;
                if (g < 3) {
                    #pragma unroll
                    for (int j = 0; j < 8; ++j) {
                        int s = (g + 1) * 8 + j;
                        Ab[nxt][j] = ldb(ap + s * 32);
                        Bb[nxt][j] = ldb(bp + s * 32);
                    }
                }
                #pragma unroll
                for (int j = 0; j < 8; ++j) {
                    if (j & 1) c1 = __builtin_amdgcn_mfma_f32_16x16x32_bf16(Ab[cur][j], Bb[cur][j], c1, 0, 0, 0);
                    else       c0 = __builtin_amdgcn_mfma_f32_16x16x32_bf16(Ab[cur][j], Bb[cur][j], c0, 0, 0, 0);
                }
            }
            f32x4 res = c0 + c1;
            int n = nb2 + n15;
            #pragma unroll
            for (int r = 0; r < 4; ++r) {
                int row = mi * 16 + q * 4 + r;
                int idx = row * 1024 + n;
                float pre = res[r] + bf2f(XH[(size_t)t * 65536 + idx]);
                float hh = tanhf(pre);
                float zv = Zbuf[idx], hv = hf32[idx];
                float hn = zv * hv + (1.f - zv) * hh;
                out[(size_t)t * 65536 + idx] = hn;
                hf32[idx] = hn;
                hbf[idx] = f2bf(hn);
                if (t == T_STEPS - 1) out[FINAL_OFF + idx] = hn;
            }
        }
        gridbar(bar);
    }
}

// ---------------- launch ----------------
extern "C" void kernel_launch(void* const* d_in, const int* in_sizes, int n_in,
                              void* d_out, int out_size, void* d_ws, size_t ws_size,
                              hipStream_t stream) {
    (void)in_sizes; (void)n_in; (void)out_size; (void)ws_size;
    const float* X     = (const float*)d_in[0];
    const float* state = (const float*)d_in[1];
    const float* Wxr   = (const float*)d_in[2];
    const float* Whr   = (const float*)d_in[3];
    const float* br    = (const float*)d_in[4];
    const float* Wxz   = (const float*)d_in[5];
    const float* Whz   = (const float*)d_in[6];
    const float* bz    = (const float*)d_in[7];
    const float* Wxh   = (const float*)d_in[8];
    const float* Whh   = (const float*)d_in[9];
    const float* bh    = (const float*)d_in[10];
    float* out = (float*)d_out;
    char* ws = (char*)d_ws;

    u16* XR   = (u16*)(ws + OFF_XR);
    u16* XZ   = (u16*)(ws + OFF_XZ);
    u16* XH   = (u16*)(ws + OFF_XH);
    u16* WXRT = (u16*)(ws + OFF_WXRT);
    u16* WXZT = (u16*)(ws + OFF_WXZT);
    u16* WXHT = (u16*)(ws + OFF_WXHT);
    u16* WHRT = (u16*)(ws + OFF_WHRT);
    u16* WHZT = (u16*)(ws + OFF_WHZT);
    u16* WHHT = (u16*)(ws + OFF_WHHT);
    u16* HBF  = (u16*)(ws + OFF_HBF);
    u16* RHBF = (u16*)(ws + OFF_RHBF);
    float* HF32 = (float*)(ws + OFF_HF32);
    float* ZBUF = (float*)(ws + OFF_ZBUF);
    unsigned* BAR = (unsigned*)(ws + OFF_BAR);

    // phase 0: transpose/convert weights ([K][N] fp32 -> [N][K] bf16) + barrier init
    transpose_cvt<<<dim3(32, 32, 6), 256, 0, stream>>>(
        Wxr, Wxz, Wxh, Whr, Whz, Whh,
        WXRT, WXZT, WXHT, WHRT, WHZT, WHHT, BAR);

    // phase 1: input projections -> bf16
    proj_gemm<<<dim3(8, 256, 3), 256, 0, stream>>>(
        X, WXRT, WXZT, WXHT, br, bz, bh, XR, XZ, XH);

    // phase 2: sequential recurrence, persistent kernel
    gru_rec<<<dim3(NBLK), 256, 0, stream>>>(
        XR, XZ, XH, WHRT, WHZT, WHHT, state,
        HBF, RHBF, HF32, ZBUF, BAR, out);
}

// Round 2
// 12790.781 us; speedup vs baseline: 1.3767x; 1.3767x over previous
//
#include <hip/hip_runtime.h>
#include <cmath>

typedef unsigned short u16;
typedef unsigned long long u64;
typedef __attribute__((ext_vector_type(4))) float f32x4;
typedef __attribute__((ext_vector_type(8))) __bf16 bf16x8;
typedef unsigned short u16x4 __attribute__((ext_vector_type(4)));
typedef unsigned short u16x8 __attribute__((ext_vector_type(8)));

#define T_STEPS 512
#define NBLK 64
#define FINAL_OFF 33554432u  // 512*64*1024

// ---------------- workspace layout (bytes) ----------------
#define OFF_XR   0ull
#define OFF_XZ   (OFF_XR + 67108864ull)     // 512*64*1024 * 2B each
#define OFF_XH   (OFF_XZ + 67108864ull)
#define OFF_WXRT (OFF_XH + 67108864ull)     // 1024*1024*2B each
#define OFF_WXZT (OFF_WXRT + 2097152ull)
#define OFF_WXHT (OFF_WXZT + 2097152ull)
#define OFF_WHRT (OFF_WXHT + 2097152ull)
#define OFF_WHZT (OFF_WHRT + 2097152ull)
#define OFF_WHHT (OFF_WHZT + 2097152ull)
#define OFF_HBF  (OFF_WHHT + 2097152ull)    // 64*1024 bf16 (cross-block, coherent)
#define OFF_RHBF (OFF_HBF + 131072ull)      // 64*1024 bf16 (cross-block, coherent)
#define OFF_HF32 (OFF_RHBF + 131072ull)     // 64*1024 f32 (block-private)
#define OFF_BAR  (OFF_HF32 + 262144ull)     // 1025 counters, 64B apart
#define BAR_BYTES 65600ull

// ---------------- helpers ----------------
__device__ __forceinline__ u16 f2bf(float f) {
    unsigned u = __builtin_bit_cast(unsigned, f);
    unsigned r = (u + 0x7FFFu + ((u >> 16) & 1u)) >> 16;
    return (u16)r;
}
__device__ __forceinline__ float bf2f(u16 h) {
    unsigned u = ((unsigned)h) << 16;
    return __builtin_bit_cast(float, u);
}
struct U64x2 { u64 lo, hi; };
__device__ __forceinline__ bf16x8 mk(u64 lo, u64 hi) {
    U64x2 t{lo, hi};
    return __builtin_bit_cast(bf16x8, t);
}
#define MFMA16 __builtin_amdgcn_mfma_f32_16x16x32_bf16

// device-coherent (agent-scope, sc0|sc1) accesses: bypass L1/L2, served by L3.
__device__ __forceinline__ u64 lda64(const u64* p) {
    return __hip_atomic_load(p, __ATOMIC_RELAXED, __HIP_MEMORY_SCOPE_AGENT);
}
__device__ __forceinline__ u16 lda16(const u16* p) {
    return __hip_atomic_load(p, __ATOMIC_RELAXED, __HIP_MEMORY_SCOPE_AGENT);
}
__device__ __forceinline__ void sta16(u16* p, u16 v) {
    __hip_atomic_store(p, v, __ATOMIC_RELAXED, __HIP_MEMORY_SCOPE_AGENT);
}

// Fence-free grid barrier: monotonic per-phase counter. Each wave drains its
// vmem (sc1 stores ack from the coherence point) before s_barrier; thread 0
// then arrives with a relaxed agent atomic and polls. No wbl2/inv anywhere.
__device__ __forceinline__ void arrive_wait(unsigned* ctr, unsigned target) {
    asm volatile("s_waitcnt vmcnt(0)" ::: "memory");
    __syncthreads();
    if (threadIdx.x == 0) {
        __hip_atomic_fetch_add(ctr, 1u, __ATOMIC_RELAXED, __HIP_MEMORY_SCOPE_AGENT);
        while (__hip_atomic_load(ctr, __ATOMIC_RELAXED, __HIP_MEMORY_SCOPE_AGENT) < target)
            __builtin_amdgcn_s_sleep(1);
    }
    __syncthreads();
}

// ---------------- phase 0: transpose + fp32->bf16 convert, [K][N] -> [N][K] ----------------
__global__ __launch_bounds__(256) void transpose_cvt(
    const float* __restrict__ W0, const float* __restrict__ W1, const float* __restrict__ W2,
    const float* __restrict__ W3, const float* __restrict__ W4, const float* __restrict__ W5,
    u16* __restrict__ D0, u16* __restrict__ D1, u16* __restrict__ D2,
    u16* __restrict__ D3, u16* __restrict__ D4, u16* __restrict__ D5)
{
    const float* S[6] = {W0, W1, W2, W3, W4, W5};
    u16* D[6] = {D0, D1, D2, D3, D4, D5};
    int z = blockIdx.z;
    const float* W = S[z];
    u16* Dt = D[z];
    __shared__ float tile[32][33];
    int bx = blockIdx.x * 32, by = blockIdx.y * 32;
    int tx = threadIdx.x & 31, ty = threadIdx.x >> 5;
    for (int i = ty; i < 32; i += 8)
        tile[i][tx] = W[(size_t)(by + i) * 1024 + bx + tx];
    __syncthreads();
    for (int i = ty; i < 32; i += 8)
        Dt[(size_t)(bx + i) * 1024 + by + tx] = f2bf(tile[tx][i]);
}

// ---------------- phase 1: X @ Wx* + b -> bf16 projections ----------------
__global__ __launch_bounds__(256, 2) void proj_gemm(
    const float* __restrict__ X,
    const u16* __restrict__ Wt0, const u16* __restrict__ Wt1, const u16* __restrict__ Wt2,
    const float* __restrict__ b0, const float* __restrict__ b1, const float* __restrict__ b2,
    u16* __restrict__ P0, u16* __restrict__ P1, u16* __restrict__ P2)
{
    int z = blockIdx.z;
    const u16* Wt = (z == 0) ? Wt0 : (z == 1) ? Wt1 : Wt2;
    const float* bias = (z == 0) ? b0 : (z == 1) ? b1 : b2;
    u16* P = (z == 0) ? P0 : (z == 1) ? P1 : P2;

    __shared__ u16 Asm[128][72];
    __shared__ u16 Bsm[128][72];

    int tid = threadIdx.x, lane = tid & 63, w = tid >> 6;
    int m0 = blockIdx.y * 128, n0 = blockIdx.x * 128;
    int mw = (w >> 1) * 64, nw = (w & 1) * 64;
    int l15 = lane & 15, lq = lane >> 4;

    f32x4 zero = {0.f, 0.f, 0.f, 0.f};
    f32x4 acc[4][4];
    #pragma unroll
    for (int mi = 0; mi < 4; ++mi)
        #pragma unroll
        for (int nj = 0; nj < 4; ++nj) acc[mi][nj] = zero;

    for (int k0 = 0; k0 < 1024; k0 += 64) {
        #pragma unroll
        for (int i = 0; i < 8; ++i) {
            int flat = i * 256 + tid;
            int r = flat >> 4, c4 = flat & 15;
            float4 v = *(const float4*)(X + (size_t)(m0 + r) * 1024 + k0 + c4 * 4);
            u16x4 pk = {f2bf(v.x), f2bf(v.y), f2bf(v.z), f2bf(v.w)};
            *(u16x4*)&Asm[r][c4 * 4] = pk;
        }
        #pragma unroll
        for (int i = 0; i < 4; ++i) {
            int flat = i * 256 + tid;
            int n = flat >> 3, seg = flat & 7;
            *(u16x8*)&Bsm[n][seg * 8] = *(const u16x8*)(Wt + (size_t)(n0 + n) * 1024 + k0 + seg * 8);
        }
        __syncthreads();
        #pragma unroll
        for (int kk = 0; kk < 2; ++kk) {
            bf16x8 af[4], bg[4];
            #pragma unroll
            for (int mi = 0; mi < 4; ++mi)
                af[mi] = *(const bf16x8*)&Asm[mw + mi * 16 + l15][kk * 32 + lq * 8];
            #pragma unroll
            for (int nj = 0; nj < 4; ++nj)
                bg[nj] = *(const bf16x8*)&Bsm[nw + nj * 16 + l15][kk * 32 + lq * 8];
            #pragma unroll
            for (int mi = 0; mi < 4; ++mi)
                #pragma unroll
                for (int nj = 0; nj < 4; ++nj)
                    acc[mi][nj] = MFMA16(af[mi], bg[nj], acc[mi][nj], 0, 0, 0);
        }
        __syncthreads();
    }
    #pragma unroll
    for (int mi = 0; mi < 4; ++mi)
        #pragma unroll
        for (int nj = 0; nj < 4; ++nj)
            #pragma unroll
            for (int r = 0; r < 4; ++r) {
                int m = m0 + mw + mi * 16 + lq * 4 + r;
                int n = n0 + nw + nj * 16 + l15;
                float v = acc[mi][nj][r] + bias[n];
                P[(size_t)m * 1024 + n] = f2bf(v);
            }
}

// ---------------- phase 2: persistent recurrent kernel ----------------
// 64 blocks x 256 thr (4 waves). Block b owns the SAME 16-col stripe for R, Z
// and H: Z and h_prev stay in registers, hf32 is block-private (plain cached),
// Whr/Whz slices persistent in LDS (64KB, swizzled), Whh slice stays L2-hot.
// Only hbf and rhbf cross blocks -> coherent (sc0|sc1) accesses, no fences.
__global__ __launch_bounds__(256, 1) void gru_rec(
    const u16* __restrict__ XR, const u16* __restrict__ XZ, const u16* __restrict__ XH,
    const u16* __restrict__ Whrt, const u16* __restrict__ Whzt, const u16* __restrict__ Whht,
    const float* __restrict__ state,
    u16* __restrict__ hbf, u16* __restrict__ rhbf, float* __restrict__ hf32,
    unsigned* __restrict__ bar, float* __restrict__ out)
{
    __shared__ u16 Wsm[32 * 1024];  // rows 0-15: Whr slice; 16-31: Whz slice

    const int b = blockIdx.x, tid = threadIdx.x;
    const int lane = tid & 63, mi = tid >> 6;
    const int n15 = lane & 15, q = lane >> 4;
    const int k7 = n15 & 7;
    const int colg = 16 * b + n15;
    const int rowA = mi * 16 + n15;

    // fill LDS weight slices (swizzled 16B chunks: phys = chunk ^ (row&7))
    {
        int row = tid >> 3, seg = tid & 7;
        const u16* src = (row < 16) ? (Whrt + (size_t)(16 * b + row) * 1024)
                                    : (Whzt + (size_t)(16 * b + row - 16) * 1024);
        #pragma unroll
        for (int v = 0; v < 16; ++v) {
            int chunk = seg * 16 + v;
            int phys = chunk ^ (row & 7);
            *(u16x8*)&Wsm[row * 1024 + phys * 8] = *(const u16x8*)(src + chunk * 8);
        }
    }
    // init h: block writes its own 16-col stripe
    for (int i = tid; i < 1024; i += 256) {
        int row = i >> 4, c = i & 15;
        int idx = row * 1024 + 16 * b + c;
        float v = state[idx];
        hf32[idx] = v;              // private
        sta16(hbf + idx, f2bf(v));  // shared
    }
    arrive_wait(bar, NBLK);  // phase 0

    const u64* hbase = (const u64*)hbf;
    const u64* rbase = (const u64*)rhbf;
    const u16* bp2 = Whht + (size_t)colg * 1024 + q * 8;

    for (int t = 0; t < T_STEPS; ++t) {
        f32x4 zreg;
        // ---------------- stage 1: R,Z; write rhbf = R*h ----------------
        {
            // early loads (hide HBM/L3 latency under MFMAs)
            u16 xr16[4], xz16[4], hv16[4];
            #pragma unroll
            for (int r = 0; r < 4; ++r) {
                int idx = (mi * 16 + q * 4 + r) * 1024 + colg;
                size_t xoff = (size_t)t * 65536 + idx;
                xr16[r] = XR[xoff];
                xz16[r] = XZ[xoff];
                hv16[r] = lda16(hbf + idx);
            }
            const u64* ap = hbase + (size_t)rowA * 256 + q * 2;
            f32x4 aRa = {0,0,0,0}, aRb = {0,0,0,0}, aZa = {0,0,0,0}, aZb = {0,0,0,0};
            u64 a0[8], a1[8];
            #pragma unroll
            for (int i = 0; i < 8; ++i) { a0[i] = lda64(ap + i * 8); a1[i] = lda64(ap + i * 8 + 1); }
            #pragma unroll
            for (int kb = 0; kb < 32; ++kb) {
                int sl = kb & 7;
                bf16x8 a = mk(a0[sl], a1[sl]);
                if (kb < 24) { a0[sl] = lda64(ap + (kb + 8) * 8); a1[sl] = lda64(ap + (kb + 8) * 8 + 1); }
                int ph = ((kb * 4 + q) ^ k7) * 8;
                bf16x8 br = *(const bf16x8*)&Wsm[n15 * 1024 + ph];
                bf16x8 bz = *(const bf16x8*)&Wsm[(16 + n15) * 1024 + ph];
                if (kb & 1) { aRb = MFMA16(a, br, aRb, 0, 0, 0); aZb = MFMA16(a, bz, aZb, 0, 0, 0); }
                else        { aRa = MFMA16(a, br, aRa, 0, 0, 0); aZa = MFMA16(a, bz, aZa, 0, 0, 0); }
            }
            f32x4 accR = aRa + aRb, accZ = aZa + aZb;
            #pragma unroll
            for (int r = 0; r < 4; ++r) {
                int idx = (mi * 16 + q * 4 + r) * 1024 + colg;
                float rpre = accR[r] + bf2f(xr16[r]);
                float zpre = accZ[r] + bf2f(xz16[r]);
                float R = 1.f / (1.f + __expf(-rpre));
                zreg[r] = 1.f / (1.f + __expf(-zpre));
                sta16(rhbf + idx, f2bf(R * bf2f(hv16[r])));
            }
        }
        arrive_wait(bar + (size_t)(1 + 2 * t) * 16, NBLK);
        // ---------------- stage 2: Hhat = tanh(Xh + (R*h)@Whh); blend ----------------
        {
            u16 xh16[4];
            float hprev[4];
            #pragma unroll
            for (int r = 0; r < 4; ++r) {
                int idx = (mi * 16 + q * 4 + r) * 1024 + colg;
                xh16[r] = XH[(size_t)t * 65536 + idx];
                hprev[r] = hf32[idx];  // private, L1/L2-hot
            }
            const u64* ap = rbase + (size_t)rowA * 256 + q * 2;
            f32x4 ca = {0,0,0,0}, cb = {0,0,0,0};
            u64 a0[8], a1[8];
            bf16x8 bbuf[4];
            #pragma unroll
            for (int i = 0; i < 8; ++i) { a0[i] = lda64(ap + i * 8); a1[i] = lda64(ap + i * 8 + 1); }
            #pragma unroll
            for (int i = 0; i < 4; ++i) bbuf[i] = *(const bf16x8*)(bp2 + i * 32);
            #pragma unroll
            for (int kb = 0; kb < 32; ++kb) {
                int sl = kb & 7;
                bf16x8 a = mk(a0[sl], a1[sl]);
                bf16x8 bb = bbuf[kb & 3];
                if (kb < 24) { a0[sl] = lda64(ap + (kb + 8) * 8); a1[sl] = lda64(ap + (kb + 8) * 8 + 1); }
                if (kb < 28) bbuf[kb & 3] = *(const bf16x8*)(bp2 + (size_t)(kb + 4) * 32);
                if (kb & 1) cb = MFMA16(a, bb, cb, 0, 0, 0);
                else        ca = MFMA16(a, bb, ca, 0, 0, 0);
            }
            f32x4 acc = ca + cb;
            #pragma unroll
            for (int r = 0; r < 4; ++r) {
                int idx = (mi * 16 + q * 4 + r) * 1024 + colg;
                size_t xoff = (size_t)t * 65536 + idx;
                float pre = acc[r] + bf2f(xh16[r]);
                float ax = fabsf(pre);
                float e = __expf(-2.f * ax);
                float th = (1.f - e) / (1.f + e);
                float hh = (pre < 0.f) ? -th : th;
                float hn = zreg[r] * hprev[r] + (1.f - zreg[r]) * hh;
                out[xoff] = hn;                 // plain (write-once, lazy writeback)
                hf32[idx] = hn;                 // private
                sta16(hbf + idx, f2bf(hn));     // shared
                if (t == T_STEPS - 1) out[FINAL_OFF + idx] = hn;
            }
        }
        arrive_wait(bar + (size_t)(2 + 2 * t) * 16, NBLK);
    }
}

// ---------------- launch ----------------
extern "C" void kernel_launch(void* const* d_in, const int* in_sizes, int n_in,
                              void* d_out, int out_size, void* d_ws, size_t ws_size,
                              hipStream_t stream) {
    (void)in_sizes; (void)n_in; (void)out_size; (void)ws_size;
    const float* X     = (const float*)d_in[0];
    const float* state = (const float*)d_in[1];
    const float* Wxr   = (const float*)d_in[2];
    const float* Whr   = (const float*)d_in[3];
    const float* br    = (const float*)d_in[4];
    const float* Wxz   = (const float*)d_in[5];
    const float* Whz   = (const float*)d_in[6];
    const float* bz    = (const float*)d_in[7];
    const float* Wxh   = (const float*)d_in[8];
    const float* Whh   = (const float*)d_in[9];
    const float* bh    = (const float*)d_in[10];
    float* out = (float*)d_out;
    char* ws = (char*)d_ws;

    u16* XR   = (u16*)(ws + OFF_XR);
    u16* XZ   = (u16*)(ws + OFF_XZ);
    u16* XH   = (u16*)(ws + OFF_XH);
    u16* WXRT = (u16*)(ws + OFF_WXRT);
    u16* WXZT = (u16*)(ws + OFF_WXZT);
    u16* WXHT = (u16*)(ws + OFF_WXHT);
    u16* WHRT = (u16*)(ws + OFF_WHRT);
    u16* WHZT = (u16*)(ws + OFF_WHZT);
    u16* WHHT = (u16*)(ws + OFF_WHHT);
    u16* HBF  = (u16*)(ws + OFF_HBF);
    u16* RHBF = (u16*)(ws + OFF_RHBF);
    float* HF32 = (float*)(ws + OFF_HF32);
    unsigned* BAR = (unsigned*)(ws + OFF_BAR);

    hipMemsetAsync(BAR, 0, BAR_BYTES, stream);

    transpose_cvt<<<dim3(32, 32, 6), 256, 0, stream>>>(
        Wxr, Wxz, Wxh, Whr, Whz, Whh,
        WXRT, WXZT, WXHT, WHRT, WHZT, WHHT);

    proj_gemm<<<dim3(8, 256, 3), 256, 0, stream>>>(
        X, WXRT, WXZT, WXHT, br, bz, bh, XR, XZ, XH);

    gru_rec<<<dim3(NBLK), 256, 0, stream>>>(
        XR, XZ, XH, WHRT, WHZT, WHHT, state,
        HBF, RHBF, HF32, BAR, out);
}